// Round 12
// baseline (423.934 us; speedup 1.0000x reference)
//
#include <hip/hip_runtime.h>
#include <hip/hip_bf16.h>
#include <stdint.h>

// KGTN round 12 = R10 with the final GEMM switched to a SINGLE-BUFFERED
// MFR=4 tile (m97 structure: 32 KiB LDS -> 4-5 blocks/CU at grid 1024).
// Lesson bank: R5/R7/R11 = three nulls on in-kernel schedule depth at
// 1-2 blocks/CU -> the lever is TLP/occupancy, not prefetch distance (m114).
// gemm_t<MFR, NBUF>: NBUF=2 = R10 2-phase double-buffer (GGNN path,
// grid-capped at 2-3 blocks/CU); NBUF=1 = single-buffer barrier loop
// (R2-proven): syncthreads -> STAGE -> syncthreads(drain) -> COMPUTE.

typedef __attribute__((ext_vector_type(8))) short bf16x8;
typedef __attribute__((ext_vector_type(4))) float f32x4;
typedef __attribute__((ext_vector_type(4))) ushort u16x4;

typedef __attribute__((address_space(3))) void lds_void;
typedef const __attribute__((address_space(1))) void gbl_void;

__device__ __forceinline__ ushort f2b(float v) {
    union { float f; uint32_t u; } c; c.f = v;
    uint32_t u = c.u + 0x7FFFu + ((c.u >> 16) & 1u);   // RNE; inputs finite
    return (ushort)(u >> 16);
}

// Tile: BM=MFR*32 x BN=128, BK=64. A row-major bf16, Bt=B^T row-major bf16.
// Grid: x=N/128, y=M/BM, z = zA*zdiv + zK. C fp32 partial z at Cv + z*cOff.
// Requires (gx*gy) % 8 == 0, K % 64 == 0, K/64 >= 2.
template <int MFR, int NBUF>
__global__ __launch_bounds__(256) void gemm_t(
    const ushort* __restrict__ A0, const ushort* __restrict__ A1,
    const ushort* __restrict__ A2, const ushort* __restrict__ Bt,
    float* __restrict__ Cv, int K, long lda01, long lda2, long ldb, long ldc,
    long aKoff, long bKa, long bKk, long cOff, int zdiv)
{
    __shared__ ushort As[NBUF * MFR * 2048];
    __shared__ ushort Bs[NBUF * 8192];
    const int tid  = threadIdx.x;
    const int lane = tid & 63;
    const int wave = tid >> 6;
    const int wr = (wave >> 1) * (MFR * 16);   // wave row band
    const int wc = (wave & 1) * 64;            // wave col band

    // T1 row-major: XCD k owns a contiguous chunk of row-major bids.
    const int gx  = gridDim.x;
    const int nwg = gx * gridDim.y;
    int h0 = blockIdx.y * gx + blockIdx.x;
    const int bid = (h0 & 7) * (nwg >> 3) + (h0 >> 3);
    const long bm = (long)(bid / gx) * (MFR * 32);
    const long bn = (long)(bid % gx) * 128;

    const int z  = blockIdx.z;
    const int zA = z / zdiv;
    const int zK = z - zA * zdiv;
    const ushort* A  = ((zA == 0) ? A0 : (zA == 1) ? A1 : A2) + (long)zK * aKoff;
    const long lda   = (zA == 2) ? lda2 : lda01;
    const ushort* Bp = Bt + (long)zA * bKa + (long)zK * bKk;

    const int l15  = lane & 15;
    const int kg   = lane >> 4;                    // 0..3
    const int srow = lane >> 3;                    // 0..7
    const int gsw  = ((lane & 7) ^ srow) & 7;      // pre-swizzled src granule

    f32x4 acc[MFR][4] = {};

    auto STAGE = [&](int k0, int buf) {
        #pragma unroll
        for (int p = 0; p < MFR; ++p) {
            const int slot = wave * MFR + p;       // BM/8 slots x 8 rows
            const int row  = slot * 8 + srow;
            const ushort* ga = A + (bm + row) * lda + (k0 + gsw * 8);
            __builtin_amdgcn_global_load_lds((gbl_void*)ga,
                (lds_void*)(As + buf * MFR * 2048 + slot * 512), 16, 0, 0);
        }
        #pragma unroll
        for (int p = 0; p < 4; ++p) {
            const int slot = wave * 4 + p;         // 16 slots x 8 rows = 128
            const int row  = slot * 8 + srow;
            const ushort* gb = Bp + (bn + row) * ldb + (k0 + gsw * 8);
            __builtin_amdgcn_global_load_lds((gbl_void*)gb,
                (lds_void*)(Bs + buf * 8192 + slot * 512), 16, 0, 0);
        }
    };

    auto COMPUTE = [&](int buf) {
        const ushort* as = As + buf * MFR * 2048;
        const ushort* bs = Bs + buf * 8192;
        #pragma unroll
        for (int kk = 0; kk < 2; ++kk) {
            const int ph = (((kk * 4 + kg) ^ (lane & 7)) & 7) * 8;
            bf16x8 af[MFR], bv[4];
            #pragma unroll
            for (int m = 0; m < MFR; ++m)
                af[m] = *(const bf16x8*)(as + (wr + m * 16 + l15) * 64 + ph);
            #pragma unroll
            for (int n = 0; n < 4; ++n)
                bv[n] = *(const bf16x8*)(bs + (wc + n * 16 + l15) * 64 + ph);
            __builtin_amdgcn_s_setprio(1);
            #pragma unroll
            for (int m = 0; m < MFR; ++m)
                #pragma unroll
                for (int n = 0; n < 4; ++n)
                    acc[m][n] = __builtin_amdgcn_mfma_f32_16x16x32_bf16(
                        af[m], bv[n], acc[m][n], 0, 0, 0);
            __builtin_amdgcn_s_setprio(0);
        }
    };

    const int T = K >> 6;
    if (NBUF == 1) {
        // m97 structure: single buffer, occupancy (not prefetch) hides latency
        for (int t = 0; t < T; ++t) {
            __syncthreads();               // all waves' compute(t-1) done
            STAGE(t * 64, 0);
            __syncthreads();               // drains vmcnt -> tile visible
            COMPUTE(0);
        }
    } else {
#define SYNC()                                              \
        __builtin_amdgcn_sched_barrier(0);                  \
        asm volatile("s_waitcnt vmcnt(0)" ::: "memory");    \
        __builtin_amdgcn_s_barrier();                       \
        __builtin_amdgcn_sched_barrier(0)
        STAGE(0, 0);
        for (int t = 0; t < T; ++t) {
            SYNC();
            if (t + 1 < T) STAGE((t + 1) * 64, (t + 1) & 1);
            COMPUTE(t & 1);
        }
#undef SYNC
    }

    // C/D layout: col = lane&15, row = (lane>>4)*4 + reg   [m89-verified]
    const int cr0 = (lane >> 4) * 4;
    float* C = Cv + cOff * z;
    #pragma unroll
    for (int m = 0; m < MFR; ++m) {
        #pragma unroll
        for (int j = 0; j < 4; ++j) {
            const long r = bm + wr + m * 16 + cr0 + j;
            #pragma unroll
            for (int n = 0; n < 4; ++n)
                C[r * ldc + bn + wc + n * 16 + l15] = acc[m][n][j];
        }
    }
}

// avn[:,0:1024] = bf16(p0+p1); avn[:,1024:2048] = bf16(p2+p3). 2048 x 256.
__global__ __launch_bounds__(256) void avn_sum_k(const float* __restrict__ p,
                                                 ushort* __restrict__ avn) {
    const long i = (long)blockIdx.x * 256 + threadIdx.x;
    const long r = i >> 8, c = (i & 255) << 2;
    const long base = r * 1024 + c;
    f32x4 a0 = *(const f32x4*)(p + base);
    f32x4 a1 = *(const f32x4*)(p + 2097152 + base);
    f32x4 b0 = *(const f32x4*)(p + 4194304 + base);
    f32x4 b1 = *(const f32x4*)(p + 6291456 + base);
    u16x4 oa, ob;
    #pragma unroll
    for (int j = 0; j < 4; ++j) {
        oa[j] = f2b(a0[j] + a1[j]);
        ob[j] = f2b(b0[j] + b1[j]);
    }
    *(u16x4*)(avn + r * 3072 + c) = oa;
    *(u16x4*)(avn + r * 3072 + 1024 + c) = ob;
}

// zv = sigmoid(zp0+zp1); rn_bf = bf16(sigmoid(rp0+rp1)*nodes). 2048 x 256.
__global__ __launch_bounds__(256) void gates_sum_k(const float* __restrict__ p,
        const float* __restrict__ nodes, float* __restrict__ zv,
        ushort* __restrict__ rn) {
    const long i = (long)blockIdx.x * 256 + threadIdx.x;
    const long r = i >> 8, c = (i & 255) << 2;
    const long base = r * 2048 + c;
    f32x4 z0 = *(const f32x4*)(p + base);
    f32x4 z1 = *(const f32x4*)(p + 4194304 + base);
    f32x4 r0 = *(const f32x4*)(p + base + 1024);
    f32x4 r1 = *(const f32x4*)(p + 4194304 + base + 1024);
    f32x4 nd = *(const f32x4*)(nodes + r * 1024 + c);
    f32x4 zo;
    u16x4 ro;
    #pragma unroll
    for (int j = 0; j < 4; ++j) {
        zo[j] = 1.f / (1.f + __expf(-(z0[j] + z1[j])));
        ro[j] = f2b(nd[j] / (1.f + __expf(-(r0[j] + r1[j]))));
    }
    *(f32x4*)(zv + r * 1024 + c) = zo;
    *(u16x4*)(rn + r * 1024 + c) = ro;
}

__global__ __launch_bounds__(256) void cvt_bf16_k(const float* __restrict__ src,
                                                  ushort* __restrict__ dst, long n4) {
    long i = (long)blockIdx.x * 256 + threadIdx.x;
    if (i >= n4) return;
    f32x4 v = *(const f32x4*)(src + i * 4);
    u16x4 o;
    #pragma unroll
    for (int j = 0; j < 4; ++j) o[j] = f2b(v[j]);
    *(u16x4*)(dst + i * 4) = o;
}

__global__ __launch_bounds__(256) void inM_dual_k(const float* __restrict__ src,
        ushort* __restrict__ dst, ushort* __restrict__ dstT) {
    __shared__ float t[32][33];
    const int c0 = blockIdx.x * 32, r0 = blockIdx.y * 32;
    const int tx = threadIdx.x & 31, ty = threadIdx.x >> 5;
    #pragma unroll
    for (int i = 0; i < 32; i += 8) {
        const float v = src[(long)(r0 + ty + i) * 2048 + c0 + tx];
        dst[(long)(r0 + ty + i) * 2048 + c0 + tx] = f2b(v);
        t[ty + i][tx] = v;
    }
    __syncthreads();
    #pragma unroll
    for (int i = 0; i < 32; i += 8)
        dstT[(long)(c0 + ty + i) * 2048 + r0 + tx] = f2b(t[tx][ty + i]);
}

__global__ __launch_bounds__(256) void wt3_k(const float* __restrict__ w3,
        const float* __restrict__ w4, const float* __restrict__ w5,
        ushort* __restrict__ Wzr, ushort* __restrict__ W5t) {
    __shared__ float t[32][33];
    const int zz = blockIdx.z;
    const float* src = (zz == 0) ? w3 : (zz == 1) ? w4 : w5;
    ushort* dst = (zz == 0) ? Wzr : (zz == 1) ? (Wzr + 3145728l) : W5t;
    const int c0 = blockIdx.x * 32, r0 = blockIdx.y * 32;
    const int tx = threadIdx.x & 31, ty = threadIdx.x >> 5;
    #pragma unroll
    for (int i = 0; i < 32; i += 8)
        t[ty + i][tx] = src[(long)(r0 + ty + i) * 1024 + c0 + tx];
    __syncthreads();
    #pragma unroll
    for (int i = 0; i < 32; i += 8)
        dst[(long)(c0 + ty + i) * 3072 + r0 + tx] = f2b(t[tx][ty + i]);
}

__global__ __launch_bounds__(256) void ut3_k(const float* __restrict__ u3,
        const float* __restrict__ u4, const float* __restrict__ u5,
        ushort* __restrict__ Wzr, ushort* __restrict__ W5t) {
    __shared__ float t[32][33];
    const int zz = blockIdx.z;
    const float* src = (zz == 0) ? u3 : (zz == 1) ? u4 : u5;
    ushort* dst = ((zz == 0) ? Wzr : (zz == 1) ? (Wzr + 3145728l) : W5t) + 2048;
    const int c0 = blockIdx.x * 32, r0 = blockIdx.y * 32;
    const int tx = threadIdx.x & 31, ty = threadIdx.x >> 5;
    #pragma unroll
    for (int i = 0; i < 32; i += 8)
        t[ty + i][tx] = src[(long)(r0 + ty + i) * 1024 + c0 + tx];
    __syncthreads();
    #pragma unroll
    for (int i = 0; i < 32; i += 8)
        dst[(long)(c0 + ty + i) * 3072 + r0 + tx] = f2b(t[tx][ty + i]);
}

__global__ __launch_bounds__(256) void transpose_cvt(const float* __restrict__ src,
                                                     ushort* __restrict__ dst,
                                                     int R, int C, int dld) {
    __shared__ float t[32][33];
    const int c0 = blockIdx.x * 32, r0 = blockIdx.y * 32;
    const int tx = threadIdx.x & 31, ty = threadIdx.x >> 5;
    #pragma unroll
    for (int i = 0; i < 32; i += 8)
        t[ty + i][tx] = src[(long)(r0 + ty + i) * C + c0 + tx];
    __syncthreads();
    #pragma unroll
    for (int i = 0; i < 32; i += 8)
        dst[(long)(c0 + ty + i) * dld + r0 + tx] = f2b(t[tx][ty + i]);
}

__global__ __launch_bounds__(256) void init_nodes_k(const float* __restrict__ lfw,
        ushort* __restrict__ nodesT, float* __restrict__ nodes,
        ushort* __restrict__ avn, ushort* __restrict__ ninit) {
    __shared__ float t[32][33];
    const int n0 = blockIdx.x * 32, h0 = blockIdx.y * 32;
    const int tx = threadIdx.x & 31, ty = threadIdx.x >> 5;
    #pragma unroll
    for (int i = 0; i < 32; i += 8) {
        float v = lfw[(long)(h0 + ty + i) * 2048 + n0 + tx];
        nodesT[(long)(h0 + ty + i) * 2048 + n0 + tx] = f2b(v);
        t[ty + i][tx] = v;
    }
    __syncthreads();
    #pragma unroll
    for (int i = 0; i < 32; i += 8) {
        const int n = n0 + ty + i, hh = h0 + tx;
        float v = t[tx][ty + i];
        nodes[(long)n * 1024 + hh] = v;
        ushort b = f2b(v);
        avn[(long)n * 3072 + 2048 + hh] = b;
        ninit[(long)n * 2048 + 1024 + hh] = b;
    }
}

__global__ __launch_bounds__(256) void update_nodes_k(float* __restrict__ nodes,
        const float* __restrict__ zv, const float* __restrict__ hp,
        ushort* __restrict__ avn, ushort* __restrict__ ninit,
        ushort* __restrict__ nodesT) {
    __shared__ float t[32][33];
    const int c0 = blockIdx.x * 32, r0 = blockIdx.y * 32;
    const int tx = threadIdx.x & 31, ty = threadIdx.x >> 5;
    #pragma unroll
    for (int i = 0; i < 32; i += 8) {
        const int r = r0 + ty + i, c = c0 + tx;
        const long idx = (long)r * 1024 + c;
        const float z = zv[idx];
        const float hsum = hp[idx] + hp[idx + 2097152] + hp[idx + 4194304];
        const float nn = (1.f - z) * nodes[idx] + z * tanhf(hsum);
        nodes[idx] = nn;
        const ushort b = f2b(nn);
        avn[(long)r * 3072 + 2048 + c] = b;
        ninit[(long)r * 2048 + c] = b;
        t[ty + i][tx] = nn;
    }
    __syncthreads();
    #pragma unroll
    for (int i = 0; i < 32; i += 8)
        nodesT[(long)(c0 + ty + i) * 2048 + r0 + tx] = f2b(t[tx][ty + i]);
}

__global__ __launch_bounds__(256) void bias_l2(const float* __restrict__ s,
        const float* __restrict__ bias, ushort* __restrict__ so_bf,
        float* __restrict__ partials) {
    __shared__ float red[256];
    const int tid = threadIdx.x;
    const long base = (long)blockIdx.x * 2048;
    float sum = 0.f;
    #pragma unroll
    for (int it = 0; it < 8; ++it) {
        const long i = base + tid + it * 256;
        const float v = s[i] + s[i + 2097152] + bias[i & 1023];
        so_bf[i] = f2b(v);
        sum += v * v;
    }
    red[tid] = sum;
    __syncthreads();
    #pragma unroll
    for (int w = 128; w > 0; w >>= 1) {
        if (tid < w) red[tid] += red[tid + w];
        __syncthreads();
    }
    if (tid == 0) partials[blockIdx.x] = red[0];
}

__global__ __launch_bounds__(256) void reduce_final(const float* __restrict__ partials,
                                                    float* __restrict__ out) {
    __shared__ float red[256];
    const int tid = threadIdx.x;
    red[tid] = partials[tid] + partials[tid + 256] + partials[tid + 512] + partials[tid + 768];
    __syncthreads();
    #pragma unroll
    for (int w = 128; w > 0; w >>= 1) {
        if (tid < w) red[tid] += red[tid + w];
        __syncthreads();
    }
    if (tid == 0) out[0] = red[0];
}

extern "C" void kernel_launch(void* const* d_in, const int* in_sizes, int n_in,
                              void* d_out, int out_size, void* d_ws, size_t ws_size,
                              hipStream_t stream) {
    const float* x   = (const float*)d_in[0];
    const float* lfw = (const float*)d_in[1];
    const float* inM = (const float*)d_in[2];
    const float* w3w = (const float*)d_in[3];
    const float* w3u = (const float*)d_in[4];
    const float* w4w = (const float*)d_in[5];
    const float* w4u = (const float*)d_in[6];
    const float* w5w = (const float*)d_in[7];
    const float* w5u = (const float*)d_in[8];
    const float* fcw = (const float*)d_in[9];
    const float* fcb = (const float*)d_in[10];
    float* out = (float*)d_out;

    const int B = 8192, N = 2048;
    const long NH = 2097152;

    float* avnp = out;                  // transient fp32 scratch in d_out
    float* zrp  = out;
    float* hpre = out;
    float* sop  = out;

    char* p = (char*)d_ws;
    auto alloc = [&](size_t bytes) {
        char* r = p; p += (bytes + 255) & ~(size_t)255; return r;
    };
    float*  nodes    = (float*)alloc(NH * 4);
    float*  zv       = (float*)alloc(NH * 4);
    float*  partials = (float*)alloc(1024 * 4);
    ushort* avn      = (ushort*)alloc(6291456ull * 2);
    ushort* rn_bf    = (ushort*)alloc(NH * 2);
    ushort* nodesT   = (ushort*)alloc(NH * 2);
    ushort* ninit    = (ushort*)alloc(4194304ull * 2);
    ushort* inM_bf   = (ushort*)alloc(4194304ull * 2);
    ushort* inMT_bf  = (ushort*)alloc(4194304ull * 2);
    ushort* Wzr_t    = (ushort*)alloc(6291456ull * 2);
    ushort* W5_t     = (ushort*)alloc(3145728ull * 2);
    ushort* fcw_t    = (ushort*)alloc(NH * 2);
    ushort* x_bf     = (ushort*)alloc(8388608ull * 2);
    ushort* so_bf    = (ushort*)alloc(NH * 2);

    const dim3 tb(256);

    // ---- prep ----
    cvt_bf16_k<<<8192, tb, 0, stream>>>(x, x_bf, 2097152);
    inM_dual_k<<<dim3(64, 64), tb, 0, stream>>>(inM, inM_bf, inMT_bf);
    wt3_k<<<dim3(32, 64, 3), tb, 0, stream>>>(w3w, w4w, w5w, Wzr_t, W5_t);
    ut3_k<<<dim3(32, 32, 3), tb, 0, stream>>>(w3u, w4u, w5u, Wzr_t, W5_t);
    transpose_cvt<<<dim3(32, 64), tb, 0, stream>>>(fcw, fcw_t, 2048, 1024, 2048);
    init_nodes_k<<<dim3(64, 32), tb, 0, stream>>>(lfw, nodesT, nodes, avn, ninit);

    // ---- GGNN time steps (R10 path, double-buffered 2-phase) ----
    for (int t = 0; t < 3; ++t) {
        gemm_t<4, 2><<<dim3(8, 16, 4), tb, 0, stream>>>(
            inM_bf, inMT_bf, nullptr, nodesT, avnp,
            1024, 2048, 0, 2048, 1024,
            1024, 0, 1024, 2097152, 2);
        avn_sum_k<<<2048, tb, 0, stream>>>(avnp, avn);
        gemm_t<4, 2><<<dim3(16, 16, 2), tb, 0, stream>>>(
            avn, nullptr, nullptr, Wzr_t, zrp,
            1536, 3072, 0, 3072, 2048,
            1536, 0, 1536, 4194304, 2);
        gates_sum_k<<<2048, tb, 0, stream>>>(zrp, nodes, zv, rn_bf);
        gemm_t<2, 2><<<dim3(8, 32, 3), tb, 0, stream>>>(
            avn, avn + 1024, rn_bf, W5_t, hpre,
            1024, 3072, 1024, 3072, 1024,
            0, 1024, 0, 2097152, 1);
        update_nodes_k<<<dim3(32, 64), tb, 0, stream>>>(nodes, zv, hpre, avn, ninit, nodesT);
    }

    gemm_t<2, 2><<<dim3(8, 32, 2), tb, 0, stream>>>(
        ninit, ninit + 1024, nullptr, fcw_t, sop,
        1024, 2048, 0, 2048, 1024,
        0, 1024, 0, 2097152, 1);
    bias_l2<<<1024, tb, 0, stream>>>(sop, fcb, so_bf, partials);
    reduce_final<<<1, tb, 0, stream>>>(partials, out + (long)B * N);
    // output = x @ step_out^T  -- single-buffered MFR=4, 1024 blocks, 4-5/CU
    gemm_t<4, 1><<<dim3(16, 64, 1), tb, 0, stream>>>(
        x_bf, nullptr, nullptr, so_bf, out,
        1024, 1024, 0, 1024, 2048,
        0, 0, 0, 0, 1);
}

// Round 13
// 413.493 us; speedup vs baseline: 1.0252x; 1.0252x over previous
//
#include <hip/hip_runtime.h>
#include <hip/hip_bf16.h>
#include <stdint.h>

// KGTN round 13 = R10 with avn GEMM switched to direct-bf16 epilogue
// (R6-proven EPI=1, MFR=2, 512 blocks) -> avn_sum deleted (3 dispatches,
// ~120MB round-trip). Final GEMM back to R10's NBUF=2 config (53.5us best).
// Lesson bank: R5/R7/R11/R12 = four nulls on GEMM schedule micro-opt at
// this problem's shapes -> GEMM family pinned ~640TF; optimize AROUND it.

typedef __attribute__((ext_vector_type(8))) short bf16x8;
typedef __attribute__((ext_vector_type(4))) float f32x4;
typedef __attribute__((ext_vector_type(4))) ushort u16x4;

typedef __attribute__((address_space(3))) void lds_void;
typedef const __attribute__((address_space(1))) void gbl_void;

__device__ __forceinline__ ushort f2b(float v) {
    union { float f; uint32_t u; } c; c.f = v;
    uint32_t u = c.u + 0x7FFFu + ((c.u >> 16) & 1u);   // RNE; inputs finite
    return (ushort)(u >> 16);
}

// Tile: BM=MFR*32 x BN=128, BK=64. A row-major bf16, Bt=B^T row-major bf16.
// Grid: x=N/128, y=M/BM, z = zA*zdiv + zK. A = A[zA] + zK*aKoff;
// B = Bt + zA*bKa + zK*bKk. EPI=0: fp32 C at Cv + z*cOff. EPI=1: bf16 C at
// (ushort*)Cv + z*cOff. Requires (gx*gy)%8==0, K%64==0, K/64>=2.
template <int MFR, int EPI>
__global__ __launch_bounds__(256) void gemm_t(
    const ushort* __restrict__ A0, const ushort* __restrict__ A1,
    const ushort* __restrict__ A2, const ushort* __restrict__ Bt,
    void* __restrict__ Cv, int K, long lda01, long lda2, long ldb, long ldc,
    long aKoff, long bKa, long bKk, long cOff, int zdiv)
{
    __shared__ ushort As[2 * MFR * 2048];
    __shared__ ushort Bs[2 * 8192];
    const int tid  = threadIdx.x;
    const int lane = tid & 63;
    const int wave = tid >> 6;
    const int wr = (wave >> 1) * (MFR * 16);   // wave row band
    const int wc = (wave & 1) * 64;            // wave col band

    // T1 row-major: XCD k owns a contiguous chunk of row-major bids.
    const int gx  = gridDim.x;
    const int nwg = gx * gridDim.y;
    int h0 = blockIdx.y * gx + blockIdx.x;
    const int bid = (h0 & 7) * (nwg >> 3) + (h0 >> 3);
    const long bm = (long)(bid / gx) * (MFR * 32);
    const long bn = (long)(bid % gx) * 128;

    const int z  = blockIdx.z;
    const int zA = z / zdiv;
    const int zK = z - zA * zdiv;
    const ushort* A  = ((zA == 0) ? A0 : (zA == 1) ? A1 : A2) + (long)zK * aKoff;
    const long lda   = (zA == 2) ? lda2 : lda01;
    const ushort* Bp = Bt + (long)zA * bKa + (long)zK * bKk;

    const int l15  = lane & 15;
    const int kg   = lane >> 4;                    // 0..3
    const int srow = lane >> 3;                    // 0..7
    const int gsw  = ((lane & 7) ^ srow) & 7;      // pre-swizzled src granule

    f32x4 acc[MFR][4] = {};

    auto STAGE = [&](int k0, int buf) {
        #pragma unroll
        for (int p = 0; p < MFR; ++p) {
            const int slot = wave * MFR + p;       // BM/8 slots x 8 rows
            const int row  = slot * 8 + srow;
            const ushort* ga = A + (bm + row) * lda + (k0 + gsw * 8);
            __builtin_amdgcn_global_load_lds((gbl_void*)ga,
                (lds_void*)(As + buf * MFR * 2048 + slot * 512), 16, 0, 0);
        }
        #pragma unroll
        for (int p = 0; p < 4; ++p) {
            const int slot = wave * 4 + p;         // 16 slots x 8 rows = 128
            const int row  = slot * 8 + srow;
            const ushort* gb = Bp + (bn + row) * ldb + (k0 + gsw * 8);
            __builtin_amdgcn_global_load_lds((gbl_void*)gb,
                (lds_void*)(Bs + buf * 8192 + slot * 512), 16, 0, 0);
        }
    };

    auto COMPUTE = [&](int buf) {
        const ushort* as = As + buf * MFR * 2048;
        const ushort* bs = Bs + buf * 8192;
        #pragma unroll
        for (int kk = 0; kk < 2; ++kk) {
            const int ph = (((kk * 4 + kg) ^ (lane & 7)) & 7) * 8;
            bf16x8 af[MFR], bv[4];
            #pragma unroll
            for (int m = 0; m < MFR; ++m)
                af[m] = *(const bf16x8*)(as + (wr + m * 16 + l15) * 64 + ph);
            #pragma unroll
            for (int n = 0; n < 4; ++n)
                bv[n] = *(const bf16x8*)(bs + (wc + n * 16 + l15) * 64 + ph);
            __builtin_amdgcn_s_setprio(1);
            #pragma unroll
            for (int m = 0; m < MFR; ++m)
                #pragma unroll
                for (int n = 0; n < 4; ++n)
                    acc[m][n] = __builtin_amdgcn_mfma_f32_16x16x32_bf16(
                        af[m], bv[n], acc[m][n], 0, 0, 0);
            __builtin_amdgcn_s_setprio(0);
        }
    };

#define SYNC()                                              \
    __builtin_amdgcn_sched_barrier(0);                      \
    asm volatile("s_waitcnt vmcnt(0)" ::: "memory");        \
    __builtin_amdgcn_s_barrier();                           \
    __builtin_amdgcn_sched_barrier(0)

    const int T = K >> 6;
    STAGE(0, 0);
    for (int t = 0; t < T; ++t) {
        SYNC();                            // tile t landed; compute t-1 done
        if (t + 1 < T) STAGE((t + 1) * 64, (t + 1) & 1);
        COMPUTE(t & 1);
    }
#undef SYNC

    // C/D layout: col = lane&15, row = (lane>>4)*4 + reg   [m89-verified]
    const int cr0 = (lane >> 4) * 4;
    #pragma unroll
    for (int m = 0; m < MFR; ++m) {
        #pragma unroll
        for (int j = 0; j < 4; ++j) {
            const long r = bm + wr + m * 16 + cr0 + j;
            #pragma unroll
            for (int n = 0; n < 4; ++n) {
                const long c = bn + wc + n * 16 + l15;
                if (EPI == 0)
                    ((float*)Cv + cOff * z)[r * ldc + c] = acc[m][n][j];
                else
                    ((ushort*)Cv + cOff * z)[r * ldc + c] = f2b(acc[m][n][j]);
            }
        }
    }
}

// zv = sigmoid(zp0+zp1); rn_bf = bf16(sigmoid(rp0+rp1)*nodes). 2048 x 256.
__global__ __launch_bounds__(256) void gates_sum_k(const float* __restrict__ p,
        const float* __restrict__ nodes, float* __restrict__ zv,
        ushort* __restrict__ rn) {
    const long i = (long)blockIdx.x * 256 + threadIdx.x;
    const long r = i >> 8, c = (i & 255) << 2;
    const long base = r * 2048 + c;
    f32x4 z0 = *(const f32x4*)(p + base);
    f32x4 z1 = *(const f32x4*)(p + 4194304 + base);
    f32x4 r0 = *(const f32x4*)(p + base + 1024);
    f32x4 r1 = *(const f32x4*)(p + 4194304 + base + 1024);
    f32x4 nd = *(const f32x4*)(nodes + r * 1024 + c);
    f32x4 zo;
    u16x4 ro;
    #pragma unroll
    for (int j = 0; j < 4; ++j) {
        zo[j] = 1.f / (1.f + __expf(-(z0[j] + z1[j])));
        ro[j] = f2b(nd[j] / (1.f + __expf(-(r0[j] + r1[j]))));
    }
    *(f32x4*)(zv + r * 1024 + c) = zo;
    *(u16x4*)(rn + r * 1024 + c) = ro;
}

__global__ __launch_bounds__(256) void cvt_bf16_k(const float* __restrict__ src,
                                                  ushort* __restrict__ dst, long n4) {
    long i = (long)blockIdx.x * 256 + threadIdx.x;
    if (i >= n4) return;
    f32x4 v = *(const f32x4*)(src + i * 4);
    u16x4 o;
    #pragma unroll
    for (int j = 0; j < 4; ++j) o[j] = f2b(v[j]);
    *(u16x4*)(dst + i * 4) = o;
}

__global__ __launch_bounds__(256) void inM_dual_k(const float* __restrict__ src,
        ushort* __restrict__ dst, ushort* __restrict__ dstT) {
    __shared__ float t[32][33];
    const int c0 = blockIdx.x * 32, r0 = blockIdx.y * 32;
    const int tx = threadIdx.x & 31, ty = threadIdx.x >> 5;
    #pragma unroll
    for (int i = 0; i < 32; i += 8) {
        const float v = src[(long)(r0 + ty + i) * 2048 + c0 + tx];
        dst[(long)(r0 + ty + i) * 2048 + c0 + tx] = f2b(v);
        t[ty + i][tx] = v;
    }
    __syncthreads();
    #pragma unroll
    for (int i = 0; i < 32; i += 8)
        dstT[(long)(c0 + ty + i) * 2048 + r0 + tx] = f2b(t[tx][ty + i]);
}

__global__ __launch_bounds__(256) void wt3_k(const float* __restrict__ w3,
        const float* __restrict__ w4, const float* __restrict__ w5,
        ushort* __restrict__ Wzr, ushort* __restrict__ W5t) {
    __shared__ float t[32][33];
    const int zz = blockIdx.z;
    const float* src = (zz == 0) ? w3 : (zz == 1) ? w4 : w5;
    ushort* dst = (zz == 0) ? Wzr : (zz == 1) ? (Wzr + 3145728l) : W5t;
    const int c0 = blockIdx.x * 32, r0 = blockIdx.y * 32;
    const int tx = threadIdx.x & 31, ty = threadIdx.x >> 5;
    #pragma unroll
    for (int i = 0; i < 32; i += 8)
        t[ty + i][tx] = src[(long)(r0 + ty + i) * 1024 + c0 + tx];
    __syncthreads();
    #pragma unroll
    for (int i = 0; i < 32; i += 8)
        dst[(long)(c0 + ty + i) * 3072 + r0 + tx] = f2b(t[tx][ty + i]);
}

__global__ __launch_bounds__(256) void ut3_k(const float* __restrict__ u3,
        const float* __restrict__ u4, const float* __restrict__ u5,
        ushort* __restrict__ Wzr, ushort* __restrict__ W5t) {
    __shared__ float t[32][33];
    const int zz = blockIdx.z;
    const float* src = (zz == 0) ? u3 : (zz == 1) ? u4 : u5;
    ushort* dst = ((zz == 0) ? Wzr : (zz == 1) ? (Wzr + 3145728l) : W5t) + 2048;
    const int c0 = blockIdx.x * 32, r0 = blockIdx.y * 32;
    const int tx = threadIdx.x & 31, ty = threadIdx.x >> 5;
    #pragma unroll
    for (int i = 0; i < 32; i += 8)
        t[ty + i][tx] = src[(long)(r0 + ty + i) * 1024 + c0 + tx];
    __syncthreads();
    #pragma unroll
    for (int i = 0; i < 32; i += 8)
        dst[(long)(c0 + ty + i) * 3072 + r0 + tx] = f2b(t[tx][ty + i]);
}

__global__ __launch_bounds__(256) void transpose_cvt(const float* __restrict__ src,
                                                     ushort* __restrict__ dst,
                                                     int R, int C, int dld) {
    __shared__ float t[32][33];
    const int c0 = blockIdx.x * 32, r0 = blockIdx.y * 32;
    const int tx = threadIdx.x & 31, ty = threadIdx.x >> 5;
    #pragma unroll
    for (int i = 0; i < 32; i += 8)
        t[ty + i][tx] = src[(long)(r0 + ty + i) * C + c0 + tx];
    __syncthreads();
    #pragma unroll
    for (int i = 0; i < 32; i += 8)
        dst[(long)(c0 + ty + i) * dld + r0 + tx] = f2b(t[tx][ty + i]);
}

__global__ __launch_bounds__(256) void init_nodes_k(const float* __restrict__ lfw,
        ushort* __restrict__ nodesT, float* __restrict__ nodes,
        ushort* __restrict__ avn, ushort* __restrict__ ninit) {
    __shared__ float t[32][33];
    const int n0 = blockIdx.x * 32, h0 = blockIdx.y * 32;
    const int tx = threadIdx.x & 31, ty = threadIdx.x >> 5;
    #pragma unroll
    for (int i = 0; i < 32; i += 8) {
        float v = lfw[(long)(h0 + ty + i) * 2048 + n0 + tx];
        nodesT[(long)(h0 + ty + i) * 2048 + n0 + tx] = f2b(v);
        t[ty + i][tx] = v;
    }
    __syncthreads();
    #pragma unroll
    for (int i = 0; i < 32; i += 8) {
        const int n = n0 + ty + i, hh = h0 + tx;
        float v = t[tx][ty + i];
        nodes[(long)n * 1024 + hh] = v;
        ushort b = f2b(v);
        avn[(long)n * 3072 + 2048 + hh] = b;
        ninit[(long)n * 2048 + 1024 + hh] = b;
    }
}

__global__ __launch_bounds__(256) void update_nodes_k(float* __restrict__ nodes,
        const float* __restrict__ zv, const float* __restrict__ hp,
        ushort* __restrict__ avn, ushort* __restrict__ ninit,
        ushort* __restrict__ nodesT) {
    __shared__ float t[32][33];
    const int c0 = blockIdx.x * 32, r0 = blockIdx.y * 32;
    const int tx = threadIdx.x & 31, ty = threadIdx.x >> 5;
    #pragma unroll
    for (int i = 0; i < 32; i += 8) {
        const int r = r0 + ty + i, c = c0 + tx;
        const long idx = (long)r * 1024 + c;
        const float z = zv[idx];
        const float hsum = hp[idx] + hp[idx + 2097152] + hp[idx + 4194304];
        const float nn = (1.f - z) * nodes[idx] + z * tanhf(hsum);
        nodes[idx] = nn;
        const ushort b = f2b(nn);
        avn[(long)r * 3072 + 2048 + c] = b;
        ninit[(long)r * 2048 + c] = b;
        t[ty + i][tx] = nn;
    }
    __syncthreads();
    #pragma unroll
    for (int i = 0; i < 32; i += 8)
        nodesT[(long)(c0 + ty + i) * 2048 + r0 + tx] = f2b(t[tx][ty + i]);
}

__global__ __launch_bounds__(256) void bias_l2(const float* __restrict__ s,
        const float* __restrict__ bias, ushort* __restrict__ so_bf,
        float* __restrict__ partials) {
    __shared__ float red[256];
    const int tid = threadIdx.x;
    const long base = (long)blockIdx.x * 2048;
    float sum = 0.f;
    #pragma unroll
    for (int it = 0; it < 8; ++it) {
        const long i = base + tid + it * 256;
        const float v = s[i] + s[i + 2097152] + bias[i & 1023];
        so_bf[i] = f2b(v);
        sum += v * v;
    }
    red[tid] = sum;
    __syncthreads();
    #pragma unroll
    for (int w = 128; w > 0; w >>= 1) {
        if (tid < w) red[tid] += red[tid + w];
        __syncthreads();
    }
    if (tid == 0) partials[blockIdx.x] = red[0];
}

__global__ __launch_bounds__(256) void reduce_final(const float* __restrict__ partials,
                                                    float* __restrict__ out) {
    __shared__ float red[256];
    const int tid = threadIdx.x;
    red[tid] = partials[tid] + partials[tid + 256] + partials[tid + 512] + partials[tid + 768];
    __syncthreads();
    #pragma unroll
    for (int w = 128; w > 0; w >>= 1) {
        if (tid < w) red[tid] += red[tid + w];
        __syncthreads();
    }
    if (tid == 0) out[0] = red[0];
}

extern "C" void kernel_launch(void* const* d_in, const int* in_sizes, int n_in,
                              void* d_out, int out_size, void* d_ws, size_t ws_size,
                              hipStream_t stream) {
    const float* x   = (const float*)d_in[0];
    const float* lfw = (const float*)d_in[1];
    const float* inM = (const float*)d_in[2];
    const float* w3w = (const float*)d_in[3];
    const float* w3u = (const float*)d_in[4];
    const float* w4w = (const float*)d_in[5];
    const float* w4u = (const float*)d_in[6];
    const float* w5w = (const float*)d_in[7];
    const float* w5u = (const float*)d_in[8];
    const float* fcw = (const float*)d_in[9];
    const float* fcb = (const float*)d_in[10];
    float* out = (float*)d_out;

    const int B = 8192, N = 2048;
    const long NH = 2097152;

    float* zrp  = out;                  // transient fp32 scratch in d_out
    float* hpre = out;
    float* sop  = out;

    char* p = (char*)d_ws;
    auto alloc = [&](size_t bytes) {
        char* r = p; p += (bytes + 255) & ~(size_t)255; return r;
    };
    float*  nodes    = (float*)alloc(NH * 4);
    float*  zv       = (float*)alloc(NH * 4);
    float*  partials = (float*)alloc(1024 * 4);
    ushort* avn      = (ushort*)alloc(6291456ull * 2);
    ushort* rn_bf    = (ushort*)alloc(NH * 2);
    ushort* nodesT   = (ushort*)alloc(NH * 2);
    ushort* ninit    = (ushort*)alloc(4194304ull * 2);
    ushort* inM_bf   = (ushort*)alloc(4194304ull * 2);
    ushort* inMT_bf  = (ushort*)alloc(4194304ull * 2);
    ushort* Wzr_t    = (ushort*)alloc(6291456ull * 2);
    ushort* W5_t     = (ushort*)alloc(3145728ull * 2);
    ushort* fcw_t    = (ushort*)alloc(NH * 2);
    ushort* x_bf     = (ushort*)alloc(8388608ull * 2);
    ushort* so_bf    = (ushort*)alloc(NH * 2);

    const dim3 tb(256);

    // ---- prep ----
    cvt_bf16_k<<<8192, tb, 0, stream>>>(x, x_bf, 2097152);
    inM_dual_k<<<dim3(64, 64), tb, 0, stream>>>(inM, inM_bf, inMT_bf);
    wt3_k<<<dim3(32, 64, 3), tb, 0, stream>>>(w3w, w4w, w5w, Wzr_t, W5_t);
    ut3_k<<<dim3(32, 32, 3), tb, 0, stream>>>(w3u, w4u, w5u, Wzr_t, W5_t);
    transpose_cvt<<<dim3(32, 64), tb, 0, stream>>>(fcw, fcw_t, 2048, 1024, 2048);
    init_nodes_k<<<dim3(64, 32), tb, 0, stream>>>(lfw, nodesT, nodes, avn, ninit);

    // ---- GGNN time steps ----
    for (int t = 0; t < 3; ++t) {
        // avn[:, z*1024 : z*1024+1024] = bf16( (z?inMT:inM) @ nodes ), direct
        gemm_t<2, 1><<<dim3(8, 32, 2), tb, 0, stream>>>(
            inM_bf, inMT_bf, nullptr, nodesT, avn,
            2048, 2048, 0, 2048, 3072,
            /*aKoff*/0, /*bKa*/0, /*bKk*/0, /*cOff*/1024, /*zdiv*/1);
        // zr partials: split-K x2 over K=3072 (R10's proven win)
        gemm_t<4, 0><<<dim3(16, 16, 2), tb, 0, stream>>>(
            avn, nullptr, nullptr, Wzr_t, zrp,
            1536, 3072, 0, 3072, 2048,
            /*aKoff*/1536, /*bKa*/0, /*bKk*/1536, /*cOff*/4194304, /*zdiv*/2);
        gates_sum_k<<<2048, tb, 0, stream>>>(zrp, nodes, zv, rn_bf);
        // hpre partials: zA in {av-low, av-high, rn}, K=1024 each
        gemm_t<2, 0><<<dim3(8, 32, 3), tb, 0, stream>>>(
            avn, avn + 1024, rn_bf, W5_t, hpre,
            1024, 3072, 1024, 3072, 1024,
            /*aKoff*/0, /*bKa*/1024, /*bKk*/0, /*cOff*/2097152, /*zdiv*/1);
        update_nodes_k<<<dim3(32, 64), tb, 0, stream>>>(nodes, zv, hpre, avn, ninit, nodesT);
    }

    // step_out partials = [nodes|init] @ fc_out_w
    gemm_t<2, 0><<<dim3(8, 32, 2), tb, 0, stream>>>(
        ninit, ninit + 1024, nullptr, fcw_t, sop,
        1024, 2048, 0, 2048, 1024,
        /*aKoff*/0, /*bKa*/1024, /*bKk*/0, /*cOff*/2097152, /*zdiv*/1);
    bias_l2<<<1024, tb, 0, stream>>>(sop, fcb, so_bf, partials);
    reduce_final<<<1, tb, 0, stream>>>(partials, out + (long)B * N);
    // output = x @ step_out^T  (R10 config: MFR=4, NBUF=2, 1024 blocks)
    gemm_t<4, 0><<<dim3(16, 64, 1), tb, 0, stream>>>(
        x_bf, nullptr, nullptr, so_bf, out,
        1024, 1024, 0, 1024, 2048,
        /*aKoff*/0, /*bKa*/0, /*bKk*/0, /*cOff*/0, /*zdiv*/1);
}

// Round 14
// 402.809 us; speedup vs baseline: 1.0524x; 1.0265x over previous
//
#include <hip/hip_runtime.h>
#include <hip/hip_bf16.h>
#include <stdint.h>

// KGTN round 14 = R13 with all INTERMEDIATE partials/gates in bf16:
// zr partials (EPI=1), hpre partials (EPI=1), zv, sop -> halves the
// inter-GEMM round-trip traffic (~150MB/call). gates_sum reads nodes_bf.
// Weight-prep transposes fused into one z=7 launch. GEMM configs = R13.
// Lesson bank: GEMM family pinned ~640TF (R5/7/11/12 nulls); fences in
// kernel = L2 thrash (R9); row-major XCD chunk for A-dominant GEMMs (R8).

typedef __attribute__((ext_vector_type(8))) short bf16x8;
typedef __attribute__((ext_vector_type(4))) float f32x4;
typedef __attribute__((ext_vector_type(4))) ushort u16x4;

typedef __attribute__((address_space(3))) void lds_void;
typedef const __attribute__((address_space(1))) void gbl_void;

__device__ __forceinline__ ushort f2b(float v) {
    union { float f; uint32_t u; } c; c.f = v;
    uint32_t u = c.u + 0x7FFFu + ((c.u >> 16) & 1u);   // RNE; inputs finite
    return (ushort)(u >> 16);
}
__device__ __forceinline__ float b2f(ushort u) {
    union { float f; uint32_t i; } c; c.i = ((uint32_t)u) << 16;
    return c.f;
}

// Tile: BM=MFR*32 x BN=128, BK=64. A row-major bf16, Bt=B^T row-major bf16.
// Grid: x=N/128, y=M/BM, z = zA*zdiv + zK. A = A[zA] + zK*aKoff;
// B = Bt + zA*bKa + zK*bKk. EPI=0: fp32 C at Cv + z*cOff. EPI=1: bf16 C at
// (ushort*)Cv + z*cOff. Requires (gx*gy)%8==0, K%64==0, K/64>=2.
template <int MFR, int EPI>
__global__ __launch_bounds__(256) void gemm_t(
    const ushort* __restrict__ A0, const ushort* __restrict__ A1,
    const ushort* __restrict__ A2, const ushort* __restrict__ Bt,
    void* __restrict__ Cv, int K, long lda01, long lda2, long ldb, long ldc,
    long aKoff, long bKa, long bKk, long cOff, int zdiv)
{
    __shared__ ushort As[2 * MFR * 2048];
    __shared__ ushort Bs[2 * 8192];
    const int tid  = threadIdx.x;
    const int lane = tid & 63;
    const int wave = tid >> 6;
    const int wr = (wave >> 1) * (MFR * 16);   // wave row band
    const int wc = (wave & 1) * 64;            // wave col band

    // T1 row-major: XCD k owns a contiguous chunk of row-major bids.
    const int gx  = gridDim.x;
    const int nwg = gx * gridDim.y;
    int h0 = blockIdx.y * gx + blockIdx.x;
    const int bid = (h0 & 7) * (nwg >> 3) + (h0 >> 3);
    const long bm = (long)(bid / gx) * (MFR * 32);
    const long bn = (long)(bid % gx) * 128;

    const int z  = blockIdx.z;
    const int zA = z / zdiv;
    const int zK = z - zA * zdiv;
    const ushort* A  = ((zA == 0) ? A0 : (zA == 1) ? A1 : A2) + (long)zK * aKoff;
    const long lda   = (zA == 2) ? lda2 : lda01;
    const ushort* Bp = Bt + (long)zA * bKa + (long)zK * bKk;

    const int l15  = lane & 15;
    const int kg   = lane >> 4;                    // 0..3
    const int srow = lane >> 3;                    // 0..7
    const int gsw  = ((lane & 7) ^ srow) & 7;      // pre-swizzled src granule

    f32x4 acc[MFR][4] = {};

    auto STAGE = [&](int k0, int buf) {
        #pragma unroll
        for (int p = 0; p < MFR; ++p) {
            const int slot = wave * MFR + p;       // BM/8 slots x 8 rows
            const int row  = slot * 8 + srow;
            const ushort* ga = A + (bm + row) * lda + (k0 + gsw * 8);
            __builtin_amdgcn_global_load_lds((gbl_void*)ga,
                (lds_void*)(As + buf * MFR * 2048 + slot * 512), 16, 0, 0);
        }
        #pragma unroll
        for (int p = 0; p < 4; ++p) {
            const int slot = wave * 4 + p;         // 16 slots x 8 rows = 128
            const int row  = slot * 8 + srow;
            const ushort* gb = Bp + (bn + row) * ldb + (k0 + gsw * 8);
            __builtin_amdgcn_global_load_lds((gbl_void*)gb,
                (lds_void*)(Bs + buf * 8192 + slot * 512), 16, 0, 0);
        }
    };

    auto COMPUTE = [&](int buf) {
        const ushort* as = As + buf * MFR * 2048;
        const ushort* bs = Bs + buf * 8192;
        #pragma unroll
        for (int kk = 0; kk < 2; ++kk) {
            const int ph = (((kk * 4 + kg) ^ (lane & 7)) & 7) * 8;
            bf16x8 af[MFR], bv[4];
            #pragma unroll
            for (int m = 0; m < MFR; ++m)
                af[m] = *(const bf16x8*)(as + (wr + m * 16 + l15) * 64 + ph);
            #pragma unroll
            for (int n = 0; n < 4; ++n)
                bv[n] = *(const bf16x8*)(bs + (wc + n * 16 + l15) * 64 + ph);
            __builtin_amdgcn_s_setprio(1);
            #pragma unroll
            for (int m = 0; m < MFR; ++m)
                #pragma unroll
                for (int n = 0; n < 4; ++n)
                    acc[m][n] = __builtin_amdgcn_mfma_f32_16x16x32_bf16(
                        af[m], bv[n], acc[m][n], 0, 0, 0);
            __builtin_amdgcn_s_setprio(0);
        }
    };

#define SYNC()                                              \
    __builtin_amdgcn_sched_barrier(0);                      \
    asm volatile("s_waitcnt vmcnt(0)" ::: "memory");        \
    __builtin_amdgcn_s_barrier();                           \
    __builtin_amdgcn_sched_barrier(0)

    const int T = K >> 6;
    STAGE(0, 0);
    for (int t = 0; t < T; ++t) {
        SYNC();                            // tile t landed; compute t-1 done
        if (t + 1 < T) STAGE((t + 1) * 64, (t + 1) & 1);
        COMPUTE(t & 1);
    }
#undef SYNC

    // C/D layout: col = lane&15, row = (lane>>4)*4 + reg   [m89-verified]
    const int cr0 = (lane >> 4) * 4;
    #pragma unroll
    for (int m = 0; m < MFR; ++m) {
        #pragma unroll
        for (int j = 0; j < 4; ++j) {
            const long r = bm + wr + m * 16 + cr0 + j;
            #pragma unroll
            for (int n = 0; n < 4; ++n) {
                const long c = bn + wc + n * 16 + l15;
                if (EPI == 0)
                    ((float*)Cv + cOff * z)[r * ldc + c] = acc[m][n][j];
                else
                    ((ushort*)Cv + cOff * z)[r * ldc + c] = f2b(acc[m][n][j]);
            }
        }
    }
}

// zv_bf = sigmoid(zp0+zp1); rn_bf = sigmoid(rp0+rp1)*nodes_bf. All bf16.
// p: ushort partials [2048,2048] x2 (z at col 0:1024, r at 1024:2048).
__global__ __launch_bounds__(256) void gates_sum_k(const ushort* __restrict__ p,
        const ushort* __restrict__ nodes_bf, ushort* __restrict__ zv,
        ushort* __restrict__ rn) {
    const long i = (long)blockIdx.x * 256 + threadIdx.x;
    const long r = i >> 8, c = (i & 255) << 2;
    const long base = r * 2048 + c;
    u16x4 z0 = *(const u16x4*)(p + base);
    u16x4 z1 = *(const u16x4*)(p + 4194304 + base);
    u16x4 r0 = *(const u16x4*)(p + base + 1024);
    u16x4 r1 = *(const u16x4*)(p + 4194304 + base + 1024);
    u16x4 nd = *(const u16x4*)(nodes_bf + r * 3072 + 2048 + c);
    u16x4 zo, ro;
    #pragma unroll
    for (int j = 0; j < 4; ++j) {
        zo[j] = f2b(1.f / (1.f + __expf(-(b2f(z0[j]) + b2f(z1[j])))));
        ro[j] = f2b(b2f(nd[j]) / (1.f + __expf(-(b2f(r0[j]) + b2f(r1[j])))));
    }
    *(u16x4*)(zv + r * 1024 + c) = zo;
    *(u16x4*)(rn + r * 1024 + c) = ro;
}

__global__ __launch_bounds__(256) void cvt_bf16_k(const float* __restrict__ src,
                                                  ushort* __restrict__ dst, long n4) {
    long i = (long)blockIdx.x * 256 + threadIdx.x;
    if (i >= n4) return;
    f32x4 v = *(const f32x4*)(src + i * 4);
    u16x4 o;
    #pragma unroll
    for (int j = 0; j < 4; ++j) o[j] = f2b(v[j]);
    *(u16x4*)(dst + i * 4) = o;
}

__global__ __launch_bounds__(256) void inM_dual_k(const float* __restrict__ src,
        ushort* __restrict__ dst, ushort* __restrict__ dstT) {
    __shared__ float t[32][33];
    const int c0 = blockIdx.x * 32, r0 = blockIdx.y * 32;
    const int tx = threadIdx.x & 31, ty = threadIdx.x >> 5;
    #pragma unroll
    for (int i = 0; i < 32; i += 8) {
        const float v = src[(long)(r0 + ty + i) * 2048 + c0 + tx];
        dst[(long)(r0 + ty + i) * 2048 + c0 + tx] = f2b(v);
        t[ty + i][tx] = v;
    }
    __syncthreads();
    #pragma unroll
    for (int i = 0; i < 32; i += 8)
        dstT[(long)(c0 + ty + i) * 2048 + r0 + tx] = f2b(t[tx][ty + i]);
}

// Fused weight transposes. z: 0..2 = W[2048,1024]->(Wzr|W5t) dld3072 off0;
// 3..5 = U[1024,1024]->same dld3072 off2048 (guard by<32); 6 = fcw->fcw_t dld2048.
__global__ __launch_bounds__(256) void wprep_k(const float* __restrict__ w3,
        const float* __restrict__ w4, const float* __restrict__ w5,
        const float* __restrict__ u3, const float* __restrict__ u4,
        const float* __restrict__ u5, const float* __restrict__ fcw,
        ushort* __restrict__ Wzr, ushort* __restrict__ W5t,
        ushort* __restrict__ fcw_t) {
    const int zz = blockIdx.z;
    if (zz >= 3 && zz < 6 && blockIdx.y >= 32) return;
    const float* src;
    ushort* dst;
    long dld;
    switch (zz) {
        case 0: src = w3;  dst = Wzr;                    dld = 3072; break;
        case 1: src = w4;  dst = Wzr + 3145728l;         dld = 3072; break;
        case 2: src = w5;  dst = W5t;                    dld = 3072; break;
        case 3: src = u3;  dst = Wzr + 2048;             dld = 3072; break;
        case 4: src = u4;  dst = Wzr + 3145728l + 2048;  dld = 3072; break;
        case 5: src = u5;  dst = W5t + 2048;             dld = 3072; break;
        default: src = fcw; dst = fcw_t;                 dld = 2048; break;
    }
    __shared__ float t[32][33];
    const int c0 = blockIdx.x * 32, r0 = blockIdx.y * 32;
    const int tx = threadIdx.x & 31, ty = threadIdx.x >> 5;
    #pragma unroll
    for (int i = 0; i < 32; i += 8)
        t[ty + i][tx] = src[(long)(r0 + ty + i) * 1024 + c0 + tx];
    __syncthreads();
    #pragma unroll
    for (int i = 0; i < 32; i += 8)
        dst[(long)(c0 + ty + i) * dld + r0 + tx] = f2b(t[tx][ty + i]);
}

__global__ __launch_bounds__(256) void init_nodes_k(const float* __restrict__ lfw,
        ushort* __restrict__ nodesT, float* __restrict__ nodes,
        ushort* __restrict__ avn, ushort* __restrict__ ninit) {
    __shared__ float t[32][33];
    const int n0 = blockIdx.x * 32, h0 = blockIdx.y * 32;
    const int tx = threadIdx.x & 31, ty = threadIdx.x >> 5;
    #pragma unroll
    for (int i = 0; i < 32; i += 8) {
        float v = lfw[(long)(h0 + ty + i) * 2048 + n0 + tx];
        nodesT[(long)(h0 + ty + i) * 2048 + n0 + tx] = f2b(v);
        t[ty + i][tx] = v;
    }
    __syncthreads();
    #pragma unroll
    for (int i = 0; i < 32; i += 8) {
        const int n = n0 + ty + i, hh = h0 + tx;
        float v = t[tx][ty + i];
        nodes[(long)n * 1024 + hh] = v;
        ushort b = f2b(v);
        avn[(long)n * 3072 + 2048 + hh] = b;
        ninit[(long)n * 2048 + 1024 + hh] = b;
    }
}

// nodes = (1-z)*nodes + z*tanh(hp0+hp1+hp2); hp,zv bf16; emits bf16 copies.
__global__ __launch_bounds__(256) void update_nodes_k(float* __restrict__ nodes,
        const ushort* __restrict__ zv, const ushort* __restrict__ hp,
        ushort* __restrict__ avn, ushort* __restrict__ ninit,
        ushort* __restrict__ nodesT) {
    __shared__ float t[32][33];
    const int c0 = blockIdx.x * 32, r0 = blockIdx.y * 32;
    const int tx = threadIdx.x & 31, ty = threadIdx.x >> 5;
    #pragma unroll
    for (int i = 0; i < 32; i += 8) {
        const int r = r0 + ty + i, c = c0 + tx;
        const long idx = (long)r * 1024 + c;
        const float z = b2f(zv[idx]);
        const float hsum = b2f(hp[idx]) + b2f(hp[idx + 2097152])
                         + b2f(hp[idx + 4194304]);
        const float nn = (1.f - z) * nodes[idx] + z * tanhf(hsum);
        nodes[idx] = nn;
        const ushort b = f2b(nn);
        avn[(long)r * 3072 + 2048 + c] = b;
        ninit[(long)r * 2048 + c] = b;
        t[ty + i][tx] = nn;
    }
    __syncthreads();
    #pragma unroll
    for (int i = 0; i < 32; i += 8)
        nodesT[(long)(c0 + ty + i) * 2048 + r0 + tx] = f2b(t[tx][ty + i]);
}

// v = sop0+sop1+bias (sop bf16); so_bf = bf16(v); partial sums of v^2.
__global__ __launch_bounds__(256) void bias_l2(const ushort* __restrict__ s,
        const float* __restrict__ bias, ushort* __restrict__ so_bf,
        float* __restrict__ partials) {
    __shared__ float red[256];
    const int tid = threadIdx.x;
    const long base = (long)blockIdx.x * 2048;
    float sum = 0.f;
    #pragma unroll
    for (int it = 0; it < 8; ++it) {
        const long i = base + tid + it * 256;
        const float v = b2f(s[i]) + b2f(s[i + 2097152]) + bias[i & 1023];
        so_bf[i] = f2b(v);
        sum += v * v;
    }
    red[tid] = sum;
    __syncthreads();
    #pragma unroll
    for (int w = 128; w > 0; w >>= 1) {
        if (tid < w) red[tid] += red[tid + w];
        __syncthreads();
    }
    if (tid == 0) partials[blockIdx.x] = red[0];
}

__global__ __launch_bounds__(256) void reduce_final(const float* __restrict__ partials,
                                                    float* __restrict__ out) {
    __shared__ float red[256];
    const int tid = threadIdx.x;
    red[tid] = partials[tid] + partials[tid + 256] + partials[tid + 512] + partials[tid + 768];
    __syncthreads();
    #pragma unroll
    for (int w = 128; w > 0; w >>= 1) {
        if (tid < w) red[tid] += red[tid + w];
        __syncthreads();
    }
    if (tid == 0) out[0] = red[0];
}

extern "C" void kernel_launch(void* const* d_in, const int* in_sizes, int n_in,
                              void* d_out, int out_size, void* d_ws, size_t ws_size,
                              hipStream_t stream) {
    const float* x   = (const float*)d_in[0];
    const float* lfw = (const float*)d_in[1];
    const float* inM = (const float*)d_in[2];
    const float* w3w = (const float*)d_in[3];
    const float* w3u = (const float*)d_in[4];
    const float* w4w = (const float*)d_in[5];
    const float* w4u = (const float*)d_in[6];
    const float* w5w = (const float*)d_in[7];
    const float* w5u = (const float*)d_in[8];
    const float* fcw = (const float*)d_in[9];
    const float* fcb = (const float*)d_in[10];
    float* out = (float*)d_out;

    const int B = 8192, N = 2048;
    const long NH = 2097152;

    // bf16 scratch regions in d_out front (each dead before next use; all
    // dead before the final GEMM rewrites d_out):
    ushort* zrp  = (ushort*)out;        // 2x [2048,2048] bf16 (16MB)
    ushort* hpre = (ushort*)out;        // 3x [2048,1024] bf16 (12MB)
    ushort* sop  = (ushort*)out;        // 2x [2048,1024] bf16 (8MB)

    char* p = (char*)d_ws;
    auto alloc = [&](size_t bytes) {
        char* r = p; p += (bytes + 255) & ~(size_t)255; return r;
    };
    float*  nodes    = (float*)alloc(NH * 4);
    float*  partials = (float*)alloc(1024 * 4);
    ushort* zv       = (ushort*)alloc(NH * 2);
    ushort* avn      = (ushort*)alloc(6291456ull * 2);
    ushort* rn_bf    = (ushort*)alloc(NH * 2);
    ushort* nodesT   = (ushort*)alloc(NH * 2);
    ushort* ninit    = (ushort*)alloc(4194304ull * 2);
    ushort* inM_bf   = (ushort*)alloc(4194304ull * 2);
    ushort* inMT_bf  = (ushort*)alloc(4194304ull * 2);
    ushort* Wzr_t    = (ushort*)alloc(6291456ull * 2);
    ushort* W5_t     = (ushort*)alloc(3145728ull * 2);
    ushort* fcw_t    = (ushort*)alloc(NH * 2);
    ushort* x_bf     = (ushort*)alloc(8388608ull * 2);
    ushort* so_bf    = (ushort*)alloc(NH * 2);

    const dim3 tb(256);

    // ---- prep (4 launches) ----
    cvt_bf16_k<<<8192, tb, 0, stream>>>(x, x_bf, 2097152);
    inM_dual_k<<<dim3(64, 64), tb, 0, stream>>>(inM, inM_bf, inMT_bf);
    wprep_k<<<dim3(32, 64, 7), tb, 0, stream>>>(w3w, w4w, w5w, w3u, w4u, w5u,
                                                fcw, Wzr_t, W5_t, fcw_t);
    init_nodes_k<<<dim3(64, 32), tb, 0, stream>>>(lfw, nodesT, nodes, avn, ninit);

    // ---- GGNN time steps ----
    for (int t = 0; t < 3; ++t) {
        // avn[:, z*1024 : +1024] = bf16( (z?inMT:inM) @ nodes ), direct epi
        gemm_t<2, 1><<<dim3(8, 32, 2), tb, 0, stream>>>(
            inM_bf, inMT_bf, nullptr, nodesT, avn,
            2048, 2048, 0, 2048, 3072,
            /*aKoff*/0, /*bKa*/0, /*bKk*/0, /*cOff*/1024, /*zdiv*/1);
        // zr bf16 partials: split-K x2 over K=3072
        gemm_t<4, 1><<<dim3(16, 16, 2), tb, 0, stream>>>(
            avn, nullptr, nullptr, Wzr_t, zrp,
            1536, 3072, 0, 3072, 2048,
            /*aKoff*/1536, /*bKa*/0, /*bKk*/1536, /*cOff*/4194304, /*zdiv*/2);
        gates_sum_k<<<2048, tb, 0, stream>>>(zrp, avn, zv, rn_bf);
        // hpre bf16 partials: zA in {av-low, av-high, rn}, K=1024 each
        gemm_t<2, 1><<<dim3(8, 32, 3), tb, 0, stream>>>(
            avn, avn + 1024, rn_bf, W5_t, hpre,
            1024, 3072, 1024, 3072, 1024,
            /*aKoff*/0, /*bKa*/1024, /*bKk*/0, /*cOff*/2097152, /*zdiv*/1);
        update_nodes_k<<<dim3(32, 64), tb, 0, stream>>>(nodes, zv, hpre, avn, ninit, nodesT);
    }

    // step_out bf16 partials = [nodes|init] @ fc_out_w
    gemm_t<2, 1><<<dim3(8, 32, 2), tb, 0, stream>>>(
        ninit, ninit + 1024, nullptr, fcw_t, sop,
        1024, 2048, 0, 2048, 1024,
        /*aKoff*/0, /*bKa*/1024, /*bKk*/0, /*cOff*/2097152, /*zdiv*/1);
    bias_l2<<<1024, tb, 0, stream>>>(sop, fcb, so_bf, partials);
    reduce_final<<<1, tb, 0, stream>>>(partials, out + (long)B * N);
    // output = x @ step_out^T  (MFR=4, NBUF=2 equivalent, 1024 blocks)
    gemm_t<4, 0><<<dim3(16, 64, 1), tb, 0, stream>>>(
        x_bf, nullptr, nullptr, so_bf, out,
        1024, 1024, 0, 1024, 2048,
        /*aKoff*/0, /*bKa*/0, /*bKk*/0, /*cOff*/0, /*zdiv*/1);
}

// Round 15
// 386.225 us; speedup vs baseline: 1.0976x; 1.0429x over previous
//
#include <hip/hip_runtime.h>
#include <hip/hip_bf16.h>
#include <stdint.h>

// KGTN round 15 = R14 + (a) fp32 nodes master deleted (update reads the
// bf16 copy in avn cols 2048:3072 in-place), (b) final GEMM -> gemm256b:
// 256x256 tile, 8 waves, progressive per-half-tile counted vmcnt schedule.
// R11's bug fixed: phases consume half-tiles in STAGING order (A0,B0,B1,A1;
// quads M0N0->M0N1->M1N1->M1N0), so each phase certifies ONE new half with
// vmcnt(6) (never 0 in loop). 3 barriers/K-tile, ds_read->MFMA waits left
// to the compiler, b0/b1 register-held across phases (24 reads / 64 MFMA).

typedef __attribute__((ext_vector_type(8))) short bf16x8;
typedef __attribute__((ext_vector_type(4))) float f32x4;
typedef __attribute__((ext_vector_type(4))) ushort u16x4;

typedef __attribute__((address_space(3))) void lds_void;
typedef const __attribute__((address_space(1))) void gbl_void;

__device__ __forceinline__ ushort f2b(float v) {
    union { float f; uint32_t u; } c; c.f = v;
    uint32_t u = c.u + 0x7FFFu + ((c.u >> 16) & 1u);   // RNE; inputs finite
    return (ushort)(u >> 16);
}
__device__ __forceinline__ float b2f(ushort u) {
    union { float f; uint32_t i; } c; c.i = ((uint32_t)u) << 16;
    return c.f;
}

#define SB __builtin_amdgcn_sched_barrier(0)

// ---------------- progressive 256x256 kernel (final GEMM) ----------------
// C[M,N] = A[M,K] @ Bt[N,K]^T, fp32 C. Grid (N/256, M/256), 512 threads.
// K % 64 == 0, K/64 >= 2, nwg % 8 == 0.
__global__ __launch_bounds__(512) void gemm256b(
    const ushort* __restrict__ A, const ushort* __restrict__ Bt,
    float* __restrict__ C, int K, long lda, long ldb, long ldc)
{
    __shared__ ushort As[2 * 16384];   // dbuf x (2 halves x 128 x 64)
    __shared__ ushort Bs[2 * 16384];
    const int tid  = threadIdx.x;
    const int lane = tid & 63;
    const int wave = tid >> 6;         // 0..7
    const int wm2  = wave >> 2;        // 0..1
    const int wn4  = wave & 3;         // 0..3

    // row-major XCD chunk remap
    const int gx  = gridDim.x;
    const int nwg = gx * gridDim.y;
    int h0 = blockIdx.y * gx + blockIdx.x;
    const int bid = (h0 & 7) * (nwg >> 3) + (h0 >> 3);
    const long bm = (long)(bid / gx) * 256;
    const long bn = (long)(bid % gx) * 256;

    const int l15 = lane & 15;
    const int kg  = lane >> 4;                 // 0..3
    const int gsw = (lane & 7) ^ (lane >> 3);  // pre-swizzled src granule

    f32x4 acc[2][2][4][2] = {};
    bf16x8 a[4][2], b0[2][2], b1[2][2];

    // which: 0=A.h0, 1=B.h0, 2=B.h1, 3=A.h1  (stage order per K-tile)
    auto STAGE_HALF = [&](int kt, int which) {
        const bool isA = (which == 0) || (which == 3);
        const int hh = (which >= 2) ? 1 : 0;
        const ushort* src = isA ? A : Bt;
        const long ld   = isA ? lda : ldb;
        const long brow = (isA ? bm : bn) + hh * 128;
        ushort* lds = (isA ? As : Bs) + (kt & 1) * 16384 + hh * 8192;
        const int k0 = kt * 64;
        #pragma unroll
        for (int p = 0; p < 2; ++p) {
            const int slot = wave * 2 + p;          // 16 slots x 8 rows
            const int row  = slot * 8 + (lane >> 3);
            const ushort* g = src + (brow + row) * ld + k0 + gsw * 8;
            __builtin_amdgcn_global_load_lds((gbl_void*)g,
                (lds_void*)(lds + slot * 512), 16, 0, 0);
        }
    };

#define LOAD_A(d, qm)                                                        \
    do {                                                                     \
        const ushort* as_ = As + (d) * 16384 + (qm) * 8192;                  \
        _Pragma("unroll")                                                    \
        for (int mi = 0; mi < 4; ++mi) {                                     \
            const int rh = wm2 * 64 + mi * 16 + l15;                         \
            _Pragma("unroll")                                                \
            for (int kk = 0; kk < 2; ++kk) {                                 \
                const int ph_ = (((kk * 4 + kg) ^ (rh & 7)) & 7) * 8;        \
                a[mi][kk] = *(const bf16x8*)(as_ + rh * 64 + ph_);           \
            }                                                                \
        }                                                                    \
    } while (0)

#define LOAD_B(d, qn, breg)                                                  \
    do {                                                                     \
        const ushort* bs_ = Bs + (d) * 16384 + (qn) * 8192;                  \
        _Pragma("unroll")                                                    \
        for (int ni = 0; ni < 2; ++ni) {                                     \
            const int rh = wn4 * 32 + ni * 16 + l15;                         \
            _Pragma("unroll")                                                \
            for (int kk = 0; kk < 2; ++kk) {                                 \
                const int ph_ = (((kk * 4 + kg) ^ (rh & 7)) & 7) * 8;        \
                breg[ni][kk] = *(const bf16x8*)(bs_ + rh * 64 + ph_);        \
            }                                                                \
        }                                                                    \
    } while (0)

#define QUAD(qm, qn, breg)                                                   \
    do {                                                                     \
        __builtin_amdgcn_s_setprio(1);                                       \
        _Pragma("unroll")                                                    \
        for (int kk = 0; kk < 2; ++kk)                                       \
            _Pragma("unroll")                                                \
            for (int mi = 0; mi < 4; ++mi)                                   \
                _Pragma("unroll")                                            \
                for (int ni = 0; ni < 2; ++ni)                               \
                    acc[qm][qn][mi][ni] =                                    \
                        __builtin_amdgcn_mfma_f32_16x16x32_bf16(             \
                            a[mi][kk], breg[ni][kk], acc[qm][qn][mi][ni],    \
                            0, 0, 0);                                        \
        __builtin_amdgcn_s_setprio(0);                                       \
    } while (0)

#define VM(n) do { SB; asm volatile("s_waitcnt vmcnt(" #n ")" ::: "memory"); \
                   SB; __builtin_amdgcn_s_barrier(); SB; } while (0)

    const int KT = K >> 6;
    STAGE_HALF(0, 0); STAGE_HALF(0, 1); STAGE_HALF(0, 2); STAGE_HALF(0, 3);
    for (int kt = 0; kt < KT; ++kt) {
        const int d  = kt & 1;
        const bool nl = (kt + 1 < KT);
        // ph0: quad (M0,N0) — needs kt.A0, kt.B0 (oldest 2 halves)
        if (nl) { STAGE_HALF(kt + 1, 0); VM(6); } else { VM(4); }
        LOAD_A(d, 0); LOAD_B(d, 0, b0);
        QUAD(0, 0, b0);
        // ph1: quad (M0,N1) — needs kt.B1
        if (nl) { STAGE_HALF(kt + 1, 1); VM(6); } else { VM(2); }
        LOAD_B(d, 1, b1);
        QUAD(0, 1, b1);
        // ph2: quad (M1,N1) — needs kt.A1
        if (nl) { STAGE_HALF(kt + 1, 2); VM(6); } else { VM(0); }
        LOAD_A(d, 1);
        QUAD(1, 1, b1);
        // ph3: quad (M1,N0) — all certified; regs a=A1, b0 held
        if (nl) STAGE_HALF(kt + 1, 3);
        QUAD(1, 0, b0);
    }
#undef VM

    // C/D layout: col = lane&15, row = (lane>>4)*4 + reg   [m89-verified]
    const int cr0 = (lane >> 4) * 4;
    #pragma unroll
    for (int qm = 0; qm < 2; ++qm)
        #pragma unroll
        for (int qn = 0; qn < 2; ++qn)
            #pragma unroll
            for (int mi = 0; mi < 4; ++mi)
                #pragma unroll
                for (int j = 0; j < 4; ++j) {
                    const long r = bm + qm * 128 + wm2 * 64 + mi * 16 + cr0 + j;
                    #pragma unroll
                    for (int ni = 0; ni < 2; ++ni)
                        C[r * ldc + bn + qn * 128 + wn4 * 32 + ni * 16 + l15] =
                            acc[qm][qn][mi][ni][j];
                }
#undef QUAD
#undef LOAD_B
#undef LOAD_A
}

// ---------------- proven 2-phase GEMM (GGNN path, = R14) ----------------
template <int MFR, int EPI>
__global__ __launch_bounds__(256) void gemm_t(
    const ushort* __restrict__ A0, const ushort* __restrict__ A1,
    const ushort* __restrict__ A2, const ushort* __restrict__ Bt,
    void* __restrict__ Cv, int K, long lda01, long lda2, long ldb, long ldc,
    long aKoff, long bKa, long bKk, long cOff, int zdiv)
{
    __shared__ ushort As[2 * MFR * 2048];
    __shared__ ushort Bs[2 * 8192];
    const int tid  = threadIdx.x;
    const int lane = tid & 63;
    const int wave = tid >> 6;
    const int wr = (wave >> 1) * (MFR * 16);
    const int wc = (wave & 1) * 64;

    const int gx  = gridDim.x;
    const int nwg = gx * gridDim.y;
    int h0 = blockIdx.y * gx + blockIdx.x;
    const int bid = (h0 & 7) * (nwg >> 3) + (h0 >> 3);
    const long bm = (long)(bid / gx) * (MFR * 32);
    const long bn = (long)(bid % gx) * 128;

    const int z  = blockIdx.z;
    const int zA = z / zdiv;
    const int zK = z - zA * zdiv;
    const ushort* A  = ((zA == 0) ? A0 : (zA == 1) ? A1 : A2) + (long)zK * aKoff;
    const long lda   = (zA == 2) ? lda2 : lda01;
    const ushort* Bp = Bt + (long)zA * bKa + (long)zK * bKk;

    const int l15  = lane & 15;
    const int kg   = lane >> 4;
    const int srow = lane >> 3;
    const int gsw  = ((lane & 7) ^ srow) & 7;

    f32x4 acc[MFR][4] = {};

    auto STAGE = [&](int k0, int buf) {
        #pragma unroll
        for (int p = 0; p < MFR; ++p) {
            const int slot = wave * MFR + p;
            const int row  = slot * 8 + srow;
            const ushort* ga = A + (bm + row) * lda + (k0 + gsw * 8);
            __builtin_amdgcn_global_load_lds((gbl_void*)ga,
                (lds_void*)(As + buf * MFR * 2048 + slot * 512), 16, 0, 0);
        }
        #pragma unroll
        for (int p = 0; p < 4; ++p) {
            const int slot = wave * 4 + p;
            const int row  = slot * 8 + srow;
            const ushort* gb = Bp + (bn + row) * ldb + (k0 + gsw * 8);
            __builtin_amdgcn_global_load_lds((gbl_void*)gb,
                (lds_void*)(Bs + buf * 8192 + slot * 512), 16, 0, 0);
        }
    };

    auto COMPUTE = [&](int buf) {
        const ushort* as = As + buf * MFR * 2048;
        const ushort* bs = Bs + buf * 8192;
        #pragma unroll
        for (int kk = 0; kk < 2; ++kk) {
            const int ph = (((kk * 4 + kg) ^ (lane & 7)) & 7) * 8;
            bf16x8 af[MFR], bv[4];
            #pragma unroll
            for (int m = 0; m < MFR; ++m)
                af[m] = *(const bf16x8*)(as + (wr + m * 16 + l15) * 64 + ph);
            #pragma unroll
            for (int n = 0; n < 4; ++n)
                bv[n] = *(const bf16x8*)(bs + (wc + n * 16 + l15) * 64 + ph);
            __builtin_amdgcn_s_setprio(1);
            #pragma unroll
            for (int m = 0; m < MFR; ++m)
                #pragma unroll
                for (int n = 0; n < 4; ++n)
                    acc[m][n] = __builtin_amdgcn_mfma_f32_16x16x32_bf16(
                        af[m], bv[n], acc[m][n], 0, 0, 0);
            __builtin_amdgcn_s_setprio(0);
        }
    };

#define SYNC()                                              \
    __builtin_amdgcn_sched_barrier(0);                      \
    asm volatile("s_waitcnt vmcnt(0)" ::: "memory");        \
    __builtin_amdgcn_s_barrier();                           \
    __builtin_amdgcn_sched_barrier(0)

    const int T = K >> 6;
    STAGE(0, 0);
    for (int t = 0; t < T; ++t) {
        SYNC();
        if (t + 1 < T) STAGE((t + 1) * 64, (t + 1) & 1);
        COMPUTE(t & 1);
    }
#undef SYNC

    const int cr0 = (lane >> 4) * 4;
    #pragma unroll
    for (int m = 0; m < MFR; ++m) {
        #pragma unroll
        for (int j = 0; j < 4; ++j) {
            const long r = bm + wr + m * 16 + cr0 + j;
            #pragma unroll
            for (int n = 0; n < 4; ++n) {
                const long c = bn + wc + n * 16 + l15;
                if (EPI == 0)
                    ((float*)Cv + cOff * z)[r * ldc + c] = acc[m][n][j];
                else
                    ((ushort*)Cv + cOff * z)[r * ldc + c] = f2b(acc[m][n][j]);
            }
        }
    }
}

// zv_bf = sigmoid(zp0+zp1); rn_bf = sigmoid(rp0+rp1)*nodes_bf(avn cols 2048:).
__global__ __launch_bounds__(256) void gates_sum_k(const ushort* __restrict__ p,
        const ushort* __restrict__ nodes_bf, ushort* __restrict__ zv,
        ushort* __restrict__ rn) {
    const long i = (long)blockIdx.x * 256 + threadIdx.x;
    const long r = i >> 8, c = (i & 255) << 2;
    const long base = r * 2048 + c;
    u16x4 z0 = *(const u16x4*)(p + base);
    u16x4 z1 = *(const u16x4*)(p + 4194304 + base);
    u16x4 r0 = *(const u16x4*)(p + base + 1024);
    u16x4 r1 = *(const u16x4*)(p + 4194304 + base + 1024);
    u16x4 nd = *(const u16x4*)(nodes_bf + r * 3072 + 2048 + c);
    u16x4 zo, ro;
    #pragma unroll
    for (int j = 0; j < 4; ++j) {
        zo[j] = f2b(1.f / (1.f + __expf(-(b2f(z0[j]) + b2f(z1[j])))));
        ro[j] = f2b(b2f(nd[j]) / (1.f + __expf(-(b2f(r0[j]) + b2f(r1[j])))));
    }
    *(u16x4*)(zv + r * 1024 + c) = zo;
    *(u16x4*)(rn + r * 1024 + c) = ro;
}

__global__ __launch_bounds__(256) void cvt_bf16_k(const float* __restrict__ src,
                                                  ushort* __restrict__ dst, long n4) {
    long i = (long)blockIdx.x * 256 + threadIdx.x;
    if (i >= n4) return;
    f32x4 v = *(const f32x4*)(src + i * 4);
    u16x4 o;
    #pragma unroll
    for (int j = 0; j < 4; ++j) o[j] = f2b(v[j]);
    *(u16x4*)(dst + i * 4) = o;
}

__global__ __launch_bounds__(256) void inM_dual_k(const float* __restrict__ src,
        ushort* __restrict__ dst, ushort* __restrict__ dstT) {
    __shared__ float t[32][33];
    const int c0 = blockIdx.x * 32, r0 = blockIdx.y * 32;
    const int tx = threadIdx.x & 31, ty = threadIdx.x >> 5;
    #pragma unroll
    for (int i = 0; i < 32; i += 8) {
        const float v = src[(long)(r0 + ty + i) * 2048 + c0 + tx];
        dst[(long)(r0 + ty + i) * 2048 + c0 + tx] = f2b(v);
        t[ty + i][tx] = v;
    }
    __syncthreads();
    #pragma unroll
    for (int i = 0; i < 32; i += 8)
        dstT[(long)(c0 + ty + i) * 2048 + r0 + tx] = f2b(t[tx][ty + i]);
}

// Fused weight transposes (z=0..6), as R14.
__global__ __launch_bounds__(256) void wprep_k(const float* __restrict__ w3,
        const float* __restrict__ w4, const float* __restrict__ w5,
        const float* __restrict__ u3, const float* __restrict__ u4,
        const float* __restrict__ u5, const float* __restrict__ fcw,
        ushort* __restrict__ Wzr, ushort* __restrict__ W5t,
        ushort* __restrict__ fcw_t) {
    const int zz = blockIdx.z;
    if (zz >= 3 && zz < 6 && blockIdx.y >= 32) return;
    const float* src;
    ushort* dst;
    long dld;
    switch (zz) {
        case 0: src = w3;  dst = Wzr;                    dld = 3072; break;
        case 1: src = w4;  dst = Wzr + 3145728l;         dld = 3072; break;
        case 2: src = w5;  dst = W5t;                    dld = 3072; break;
        case 3: src = u3;  dst = Wzr + 2048;             dld = 3072; break;
        case 4: src = u4;  dst = Wzr + 3145728l + 2048;  dld = 3072; break;
        case 5: src = u5;  dst = W5t + 2048;             dld = 3072; break;
        default: src = fcw; dst = fcw_t;                 dld = 2048; break;
    }
    __shared__ float t[32][33];
    const int c0 = blockIdx.x * 32, r0 = blockIdx.y * 32;
    const int tx = threadIdx.x & 31, ty = threadIdx.x >> 5;
    #pragma unroll
    for (int i = 0; i < 32; i += 8)
        t[ty + i][tx] = src[(long)(r0 + ty + i) * 1024 + c0 + tx];
    __syncthreads();
    #pragma unroll
    for (int i = 0; i < 32; i += 8)
        dst[(long)(c0 + ty + i) * dld + r0 + tx] = f2b(t[tx][ty + i]);
}

// init: nodesT_bf, nodes_bf -> avn cols 2048:3072, init_bf -> ninit cols
// 1024:2048. (fp32 nodes master deleted.)
__global__ __launch_bounds__(256) void init_nodes_k(const float* __restrict__ lfw,
        ushort* __restrict__ nodesT, ushort* __restrict__ avn,
        ushort* __restrict__ ninit) {
    __shared__ float t[32][33];
    const int n0 = blockIdx.x * 32, h0 = blockIdx.y * 32;
    const int tx = threadIdx.x & 31, ty = threadIdx.x >> 5;
    #pragma unroll
    for (int i = 0; i < 32; i += 8) {
        float v = lfw[(long)(h0 + ty + i) * 2048 + n0 + tx];
        nodesT[(long)(h0 + ty + i) * 2048 + n0 + tx] = f2b(v);
        t[ty + i][tx] = v;
    }
    __syncthreads();
    #pragma unroll
    for (int i = 0; i < 32; i += 8) {
        const int n = n0 + ty + i, hh = h0 + tx;
        ushort b = f2b(t[tx][ty + i]);
        avn[(long)n * 3072 + 2048 + hh] = b;
        ninit[(long)n * 2048 + 1024 + hh] = b;
    }
}

// nodes_new = (1-z)*nodes_bf + z*tanh(hp0+hp1+hp2); nodes_bf read from avn
// cols 2048:3072 IN-PLACE (each element read then written by its own thread).
__global__ __launch_bounds__(256) void update_nodes_k(
        const ushort* __restrict__ zv, const ushort* __restrict__ hp,
        ushort* __restrict__ avn, ushort* __restrict__ ninit,
        ushort* __restrict__ nodesT) {
    __shared__ float t[32][33];
    const int c0 = blockIdx.x * 32, r0 = blockIdx.y * 32;
    const int tx = threadIdx.x & 31, ty = threadIdx.x >> 5;
    #pragma unroll
    for (int i = 0; i < 32; i += 8) {
        const int r = r0 + ty + i, c = c0 + tx;
        const long idx = (long)r * 1024 + c;
        const float z = b2f(zv[idx]);
        const float n_old = b2f(avn[(long)r * 3072 + 2048 + c]);
        const float hsum = b2f(hp[idx]) + b2f(hp[idx + 2097152])
                         + b2f(hp[idx + 4194304]);
        const float nn = (1.f - z) * n_old + z * tanhf(hsum);
        const ushort b = f2b(nn);
        avn[(long)r * 3072 + 2048 + c] = b;
        ninit[(long)r * 2048 + c] = b;
        t[ty + i][tx] = nn;
    }
    __syncthreads();
    #pragma unroll
    for (int i = 0; i < 32; i += 8)
        nodesT[(long)(c0 + ty + i) * 2048 + r0 + tx] = f2b(t[tx][ty + i]);
}

// v = sop0+sop1+bias (sop bf16); so_bf = bf16(v); partial sums of v^2.
__global__ __launch_bounds__(256) void bias_l2(const ushort* __restrict__ s,
        const float* __restrict__ bias, ushort* __restrict__ so_bf,
        float* __restrict__ partials) {
    __shared__ float red[256];
    const int tid = threadIdx.x;
    const long base = (long)blockIdx.x * 2048;
    float sum = 0.f;
    #pragma unroll
    for (int it = 0; it < 8; ++it) {
        const long i = base + tid + it * 256;
        const float v = b2f(s[i]) + b2f(s[i + 2097152]) + bias[i & 1023];
        so_bf[i] = f2b(v);
        sum += v * v;
    }
    red[tid] = sum;
    __syncthreads();
    #pragma unroll
    for (int w = 128; w > 0; w >>= 1) {
        if (tid < w) red[tid] += red[tid + w];
        __syncthreads();
    }
    if (tid == 0) partials[blockIdx.x] = red[0];
}

__global__ __launch_bounds__(256) void reduce_final(const float* __restrict__ partials,
                                                    float* __restrict__ out) {
    __shared__ float red[256];
    const int tid = threadIdx.x;
    red[tid] = partials[tid] + partials[tid + 256] + partials[tid + 512] + partials[tid + 768];
    __syncthreads();
    #pragma unroll
    for (int w = 128; w > 0; w >>= 1) {
        if (tid < w) red[tid] += red[tid + w];
        __syncthreads();
    }
    if (tid == 0) out[0] = red[0];
}

extern "C" void kernel_launch(void* const* d_in, const int* in_sizes, int n_in,
                              void* d_out, int out_size, void* d_ws, size_t ws_size,
                              hipStream_t stream) {
    const float* x   = (const float*)d_in[0];
    const float* lfw = (const float*)d_in[1];
    const float* inM = (const float*)d_in[2];
    const float* w3w = (const float*)d_in[3];
    const float* w3u = (const float*)d_in[4];
    const float* w4w = (const float*)d_in[5];
    const float* w4u = (const float*)d_in[6];
    const float* w5w = (const float*)d_in[7];
    const float* w5u = (const float*)d_in[8];
    const float* fcw = (const float*)d_in[9];
    const float* fcb = (const float*)d_in[10];
    float* out = (float*)d_out;

    const int B = 8192, N = 2048;
    const long NH = 2097152;

    ushort* zrp  = (ushort*)out;        // 2x [2048,2048] bf16 scratch
    ushort* hpre = (ushort*)out;        // 3x [2048,1024] bf16
    ushort* sop  = (ushort*)out;        // 2x [2048,1024] bf16

    char* p = (char*)d_ws;
    auto alloc = [&](size_t bytes) {
        char* r = p; p += (bytes + 255) & ~(size_t)255; return r;
    };
    float*  partials = (float*)alloc(1024 * 4);
    ushort* zv       = (ushort*)alloc(NH * 2);
    ushort* avn      = (ushort*)alloc(6291456ull * 2);
    ushort* rn_bf    = (ushort*)alloc(NH * 2);
    ushort* nodesT   = (ushort*)alloc(NH * 2);
    ushort* ninit    = (ushort*)alloc(4194304ull * 2);
    ushort* inM_bf   = (ushort*)alloc(4194304ull * 2);
    ushort* inMT_bf  = (ushort*)alloc(4194304ull * 2);
    ushort* Wzr_t    = (ushort*)alloc(6291456ull * 2);
    ushort* W5_t     = (ushort*)alloc(3145728ull * 2);
    ushort* fcw_t    = (ushort*)alloc(NH * 2);
    ushort* x_bf     = (ushort*)alloc(8388608ull * 2);
    ushort* so_bf    = (ushort*)alloc(NH * 2);

    const dim3 tb(256);

    // ---- prep ----
    cvt_bf16_k<<<8192, tb, 0, stream>>>(x, x_bf, 2097152);
    inM_dual_k<<<dim3(64, 64), tb, 0, stream>>>(inM, inM_bf, inMT_bf);
    wprep_k<<<dim3(32, 64, 7), tb, 0, stream>>>(w3w, w4w, w5w, w3u, w4u, w5u,
                                                fcw, Wzr_t, W5_t, fcw_t);
    init_nodes_k<<<dim3(64, 32), tb, 0, stream>>>(lfw, nodesT, avn, ninit);

    // ---- GGNN time steps ----
    for (int t = 0; t < 3; ++t) {
        gemm_t<2, 1><<<dim3(8, 32, 2), tb, 0, stream>>>(
            inM_bf, inMT_bf, nullptr, nodesT, avn,
            2048, 2048, 0, 2048, 3072,
            0, 0, 0, 1024, 1);
        gemm_t<4, 1><<<dim3(16, 16, 2), tb, 0, stream>>>(
            avn, nullptr, nullptr, Wzr_t, zrp,
            1536, 3072, 0, 3072, 2048,
            1536, 0, 1536, 4194304, 2);
        gates_sum_k<<<2048, tb, 0, stream>>>(zrp, avn, zv, rn_bf);
        gemm_t<2, 1><<<dim3(8, 32, 3), tb, 0, stream>>>(
            avn, avn + 1024, rn_bf, W5_t, hpre,
            1024, 3072, 1024, 3072, 1024,
            0, 1024, 0, 2097152, 1);
        update_nodes_k<<<dim3(32, 64), tb, 0, stream>>>(zv, hpre, avn, ninit, nodesT);
    }

    gemm_t<2, 1><<<dim3(8, 32, 2), tb, 0, stream>>>(
        ninit, ninit + 1024, nullptr, fcw_t, sop,
        1024, 2048, 0, 2048, 1024,
        0, 1024, 0, 2097152, 1);
    bias_l2<<<1024, tb, 0, stream>>>(sop, fcb, so_bf, partials);
    reduce_final<<<1, tb, 0, stream>>>(partials, out + (long)B * N);
    // output = x @ step_out^T : progressive 256x256 kernel, 256 blocks
    gemm256b<<<dim3(8, 32), 512, 0, stream>>>(x_bf, so_bf, out,
                                              1024, 1024, 1024, 2048);
}